// Round 18
// baseline (223.316 us; speedup 1.0000x reference)
//
#include <hip/hip_runtime.h>
#include <stdint.h>

#define T_TOK 4096
#define H_DIM 1024
#define E_NUM 16
#define I_DIM 512
#define IS_DIM 2048
#define TOPK 4
#define NGRP 4
#define GSZ 4
#define MAXMT 32
#define NCHUNK 64  // (T_TOK*TOPK)/256

// weight-cvt segment boundaries in float4 units (wsu, wsd, wu, wd)
#define W0 524288
#define W1 1048576
#define W2 3145728
#define W3 5242880
#define CVT_NB 2048

typedef unsigned short u16;
typedef __attribute__((ext_vector_type(8))) short short8;
typedef __attribute__((ext_vector_type(4))) float f32x4;

__device__ __forceinline__ void gload16(const void* g, void* l) {
  __builtin_amdgcn_global_load_lds(
      (const __attribute__((address_space(1))) void*)g,
      (__attribute__((address_space(3))) void*)l, 16, 0, 0);
}

__device__ __forceinline__ u16 f2bf(float f) {
  union { float f; uint32_t u; } v; v.f = f;
  uint32_t u = v.u;
  uint32_t r = (u + 0x7fffu + ((u >> 16) & 1u)) >> 16;
  return (u16)r;
}

__device__ __forceinline__ float bf2f(u16 h) {
  union { uint32_t u; float f; } v; v.u = ((uint32_t)h) << 16;
  return v.f;
}

// ---------------- weights fp32 -> bf16 (grid-stride, 4 segments) ----------
__global__ __launch_bounds__(256) void cvt_w_kernel(
    const float* __restrict__ wsu, const float* __restrict__ wsd,
    const float* __restrict__ wu, const float* __restrict__ wd,
    u16* __restrict__ wsub, u16* __restrict__ wsdb,
    u16* __restrict__ wub, u16* __restrict__ wdb) {
  for (int i = blockIdx.x * 256 + threadIdx.x; i < W3; i += CVT_NB * 256) {
    const float4* src; ushort4* dst; int base;
    if (i < W0)      { src = (const float4*)wsu; dst = (ushort4*)wsub; base = 0;  }
    else if (i < W1) { src = (const float4*)wsd; dst = (ushort4*)wsdb; base = W0; }
    else if (i < W2) { src = (const float4*)wu;  dst = (ushort4*)wub;  base = W1; }
    else             { src = (const float4*)wd;  dst = (ushort4*)wdb;  base = W2; }
    float4 v = src[i - base];
    ushort4 o;
    o.x = f2bf(v.x); o.y = f2bf(v.y); o.z = f2bf(v.z); o.w = f2bf(v.w);
    dst[i - base] = o;
  }
}

// ------- routing: per-token top-4 (no atomics) + x fp32->bf16 side-write ---
__global__ __launch_bounds__(256) void route_kernel(
    const float* __restrict__ x, const float* __restrict__ rw,
    const float* __restrict__ bias, int* __restrict__ tidx_out,
    float* __restrict__ tw_out, u16* __restrict__ x_bf) {
  const int wave = threadIdx.x >> 6;
  const int lane = threadIdx.x & 63;
  const int t = blockIdx.x * 4 + wave;

  const float4* xr = reinterpret_cast<const float4*>(x + (size_t)t * H_DIM);
  const float4* rw4 = reinterpret_cast<const float4*>(rw);
  ushort4* xbw = reinterpret_cast<ushort4*>(x_bf + (size_t)t * H_DIM);
  float4 xv[4];
#pragma unroll
  for (int j = 0; j < 4; ++j) xv[j] = xr[lane + j * 64];
#pragma unroll
  for (int j = 0; j < 4; ++j) {
    ushort4 o;
    o.x = f2bf(xv[j].x); o.y = f2bf(xv[j].y);
    o.z = f2bf(xv[j].z); o.w = f2bf(xv[j].w);
    xbw[lane + j * 64] = o;
  }

  double acc[E_NUM];
#pragma unroll
  for (int e = 0; e < E_NUM; ++e) {
    double a = 0.0;
#pragma unroll
    for (int j = 0; j < 4; ++j) {
      float4 w = rw4[e * 256 + lane + j * 64];
      a += (double)xv[j].x * (double)w.x;
      a += (double)xv[j].y * (double)w.y;
      a += (double)xv[j].z * (double)w.z;
      a += (double)xv[j].w * (double)w.w;
    }
    acc[e] = a;
  }
#pragma unroll
  for (int e = 0; e < E_NUM; ++e) {
#pragma unroll
    for (int off = 32; off; off >>= 1) acc[e] += __shfl_xor(acc[e], off);
  }
  if (lane == 0) {
    float scores[E_NUM], sfc[E_NUM];
#pragma unroll
    for (int e = 0; e < E_NUM; ++e) {
      scores[e] = 1.0f / (1.0f + expf((float)(-acc[e])));
      sfc[e] = scores[e] + bias[e];
    }
    float gs[NGRP];
#pragma unroll
    for (int g = 0; g < NGRP; ++g) {
      float m1 = -1e30f, m2 = -1e30f;
#pragma unroll
      for (int j = 0; j < GSZ; ++j) {
        float v = sfc[g * GSZ + j];
        if (v > m1) { m2 = m1; m1 = v; } else if (v > m2) { m2 = v; }
      }
      gs[g] = m1 + m2;
    }
    int g1 = 0;
    for (int g = 1; g < NGRP; ++g) if (gs[g] > gs[g1]) g1 = g;
    int g2 = -1;
    for (int g = 0; g < NGRP; ++g) {
      if (g == g1) continue;
      if (g2 < 0 || gs[g] > gs[g2]) g2 = g;
    }
    float masked[E_NUM];
#pragma unroll
    for (int e = 0; e < E_NUM; ++e) {
      int g = e / GSZ;
      masked[e] = (g == g1 || g == g2) ? sfc[e] : 0.0f;
    }
    int tidx[TOPK]; float tw[TOPK];
#pragma unroll
    for (int k = 0; k < TOPK; ++k) {
      int best = 0; float bv = masked[0];
      for (int e = 1; e < E_NUM; ++e)
        if (masked[e] > bv) { bv = masked[e]; best = e; }
      tidx[k] = best; tw[k] = scores[best]; masked[best] = -1e30f;
    }
    float s = tw[0] + tw[1] + tw[2] + tw[3] + 1e-20f;
#pragma unroll
    for (int k = 0; k < TOPK; ++k) {
      tidx_out[t * TOPK + k] = tidx[k];
      tw_out[t * TOPK + k] = tw[k] / s * 2.5f;
    }
  }
}

// ---------------- chunk histogram (64 blocks, one barrier) ----------------
__global__ __launch_bounds__(256) void hist_kernel(const int* __restrict__ tidx,
                                                   int* __restrict__ partial) {
  const int c = blockIdx.x;
  const int tid = threadIdx.x;
  const int lane = tid & 63;
  const int w = tid >> 6;
  __shared__ int h[4][E_NUM];
  const int e = tidx[c * 256 + tid];
#pragma unroll
  for (int ee = 0; ee < E_NUM; ++ee) {
    unsigned long long b = __ballot(e == ee);
    if (lane == 0) h[w][ee] = __popcll(b);
  }
  __syncthreads();
  if (tid < E_NUM)
    partial[c * E_NUM + tid] = h[0][tid] + h[1][tid] + h[2][tid] + h[3][tid];
}

// ------- per-expert chunk bases + expert offsets (1 block) -------
__global__ __launch_bounds__(256) void prefix2_kernel(
    const int* __restrict__ partial, int* __restrict__ chunk_base,
    int* __restrict__ counts, int* __restrict__ offsets) {
  __shared__ int tot[E_NUM];
  __shared__ int offs[E_NUM];
  const int tid = threadIdx.x;
  if (tid < E_NUM) {
    int run = 0;
    for (int c = 0; c < NCHUNK; ++c) {
      chunk_base[c * E_NUM + tid] = run;
      run += partial[c * E_NUM + tid];
    }
    tot[tid] = run;
    counts[tid] = run;
  }
  __syncthreads();
  if (tid == 0) {
    int s = 0;
    for (int e = 0; e < E_NUM; ++e) { offs[e] = s; offsets[e] = s; s += tot[e]; }
    offsets[E_NUM] = s;
  }
  __syncthreads();
  for (int i = tid; i < NCHUNK * E_NUM; i += 256)
    chunk_base[i] += offs[i & 15];
}

// ---------------- scatter (64 blocks, one barrier) ----------------
__global__ __launch_bounds__(256) void scatter2_kernel(
    const int* __restrict__ tidx, const float* __restrict__ tw,
    const int* __restrict__ chunk_base,
    int* __restrict__ tok_g, float* __restrict__ w_g, int* __restrict__ pos_map) {
  const int c = blockIdx.x;
  const int tid = threadIdx.x;
  const int lane = tid & 63;
  const int w = tid >> 6;
  __shared__ int h[4][E_NUM];
  const int i = c * 256 + tid;
  const int e = tidx[i];
  int pre = 0;
#pragma unroll
  for (int ee = 0; ee < E_NUM; ++ee) {
    unsigned long long b = __ballot(e == ee);
    if (lane == 0) h[w][ee] = __popcll(b);
    if (ee == e) pre = __popcll(b & ((1ull << lane) - 1ull));
  }
  __syncthreads();
  int rank = pre;
  for (int ww = 0; ww < w; ++ww) rank += h[ww][e];
  const int pos = chunk_base[c * E_NUM + e] + rank;
  tok_g[pos] = i >> 2;
  w_g[pos] = tw[i];
  pos_map[i] = pos;
}

// ---- merged UP GEMM: 128x64 tile, 4 waves, BK=64, TRI-buffer 72KB --------
// counted vmcnt(6) (never 0 mid-loop), depth-2 prefetch, 2 blocks/CU.
#define NB_UP 5120
__global__ __launch_bounds__(256, 2) void gemm_up(
    const u16* __restrict__ x_bf, const u16* __restrict__ wsup_bf,
    const u16* __restrict__ wup_bf, u16* __restrict__ hs, u16* __restrict__ hp,
    const int* __restrict__ counts, const int* __restrict__ offsets,
    const int* __restrict__ tok_g, const float* __restrict__ w_g) {
  __shared__ __align__(16) u16 As[3][128 * 64];  // 48 KB
  __shared__ __align__(16) u16 Bs[3][64 * 64];   // 24 KB

  const int cpx = gridDim.x >> 3;
  const int wg = (blockIdx.x & 7) * cpx + (blockIdx.x >> 3);
  const int q = wg / 5;
  const int r5 = wg - q * 5;
  const bool shared = (r5 == 0);

  int mt, nt, cnt, obase = 0;
  const u16* B;
  if (shared) {
    mt = q >> 5;            // IS_DIM/64 = 32 n-tiles
    nt = q & 31;
    cnt = T_TOK;
    B = wsup_bf;
  } else {
    int rid = q * 4 + (r5 - 1);       // 0..4095
    int e = rid >> 8;                 // 256 slots/expert
    int r = rid & 255;
    mt = r >> 3;                      // MAXMT=32 m-tiles
    nt = r & 7;                       // I_DIM/64 = 8 n-tiles
    cnt = counts[e];
    if (mt * 128 >= cnt) return;
    obase = offsets[e];
    B = wup_bf + (size_t)e * (I_DIM * H_DIM);
  }
  const int K = H_DIM;

  const int tid = threadIdx.x;
  const int srow = tid >> 3;
  const int slot = tid & 7;
  const u16* gA[4];
#pragma unroll
  for (int p = 0; p < 4; ++p) {
    int rloc = p * 32 + srow;
    int ks = ((slot ^ (rloc & 7)) << 3);
    int am = mt * 128 + rloc;
    int row;
    if (shared) row = am;
    else row = tok_g[obase + ((am < cnt) ? am : 0)];
    gA[p] = x_bf + (size_t)row * H_DIM + ks;
  }
  const u16* gB[2];
#pragma unroll
  for (int p = 0; p < 2; ++p) {
    int rloc = p * 32 + srow;
    int ks = ((slot ^ (rloc & 7)) << 3);
    gB[p] = B + (size_t)(nt * 64 + rloc) * K + ks;
  }

  const int wave = tid >> 6;
  const int lane = tid & 63;
  const int wr = wave >> 1;
  const int wc = wave & 1;
  const int frow = lane & 15;
  const int l4 = lane >> 4;

  int a_off[4][2], b_off[2][2];
#pragma unroll
  for (int m = 0; m < 4; ++m) {
    int row = wr * 64 + m * 16 + frow;
#pragma unroll
    for (int kk = 0; kk < 2; ++kk)
      a_off[m][kk] = (row << 6) + ((((kk << 2) + l4) ^ (row & 7)) << 3);
  }
#pragma unroll
  for (int n = 0; n < 2; ++n) {
    int row = wc * 32 + n * 16 + frow;
#pragma unroll
    for (int kk = 0; kk < 2; ++kk)
      b_off[n][kk] = (row << 6) + ((((kk << 2) + l4) ^ (row & 7)) << 3);
  }

  f32x4 acc[4][2];
#pragma unroll
  for (int m = 0; m < 4; ++m)
#pragma unroll
    for (int n = 0; n < 2; ++n) acc[m][n] = (f32x4)0.0f;

  const int dst = tid << 3;
  auto stage = [&](int k0, int c) {
#pragma unroll
    for (int p = 0; p < 4; ++p)
      gload16(gA[p] + k0, &As[c][(p << 11) + dst]);
#pragma unroll
    for (int p = 0; p < 2; ++p)
      gload16(gB[p] + k0, &Bs[c][(p << 11) + dst]);
  };

  const int KT = K >> 6;  // 16
  stage(0, 0);
  stage(64, 1);
  int cb = 0, sb = 2;
  for (int kt = 0; kt < KT; ++kt) {
    if (kt < KT - 1) {
      asm volatile("s_waitcnt vmcnt(6)" ::: "memory");
    } else {
      asm volatile("s_waitcnt vmcnt(0)" ::: "memory");
    }
    __builtin_amdgcn_s_barrier();
    __builtin_amdgcn_sched_barrier(0);
    if (kt + 2 < KT) stage((kt + 2) << 6, sb);
#pragma unroll
    for (int kk = 0; kk < 2; ++kk) {
      short8 a[4], b[2];
#pragma unroll
      for (int m = 0; m < 4; ++m)
        a[m] = *reinterpret_cast<const short8*>(&As[cb][a_off[m][kk]]);
#pragma unroll
      for (int n = 0; n < 2; ++n)
        b[n] = *reinterpret_cast<const short8*>(&Bs[cb][b_off[n][kk]]);
      __builtin_amdgcn_s_setprio(1);
#pragma unroll
      for (int m = 0; m < 4; ++m)
#pragma unroll
        for (int n = 0; n < 2; ++n)
          acc[m][n] = __builtin_amdgcn_mfma_f32_16x16x32_bf16(a[m], b[n], acc[m][n], 0, 0, 0);
      __builtin_amdgcn_s_setprio(0);
    }
    cb = (cb == 2) ? 0 : cb + 1;
    sb = (sb == 2) ? 0 : sb + 1;
  }

  const int rbase = l4 << 2;
  const int cbase = frow;
#pragma unroll
  for (int m = 0; m < 4; ++m) {
#pragma unroll
    for (int r = 0; r < 4; ++r) {
      int lr = wr * 64 + (m << 4) + rbase + r;
      int grow = mt * 128 + lr;
      if (!shared && grow >= cnt) continue;
      float wv = shared ? 1.0f : w_g[obase + grow];
#pragma unroll
      for (int n = 0; n < 2; ++n) {
        int gc = nt * 64 + wc * 32 + (n << 4) + cbase;
        float v = acc[m][n][r];
        float tpos = fmaxf(v, 0.0f);
        float o = tpos * tpos * wv;
        if (shared) hs[(size_t)grow * IS_DIM + gc] = f2bf(o);
        else hp[(size_t)(obase + grow) * I_DIM + gc] = f2bf(o);
      }
    }
  }
}

// ---- bf16 MFMA GEMM down-path (tri-buffer BK=64 counted-vmcnt) -----------
// EPI 1: shared-down : out[t] = acc + sum_k bf2f(Rd[pos_map[t*4+k]])
// EPI 3: routed-down : C=Rd bf16 plain store at row obase+grow
template <int EPI>
__global__ __launch_bounds__(256, 2) void gemm_bt(
    const u16* __restrict__ Abase, const u16* __restrict__ Bbase,
    float* __restrict__ Cf, u16* __restrict__ Cb,
    int M, int N, int K,
    const int* __restrict__ counts, const int* __restrict__ offsets,
    const int* __restrict__ tok_g, const float* __restrict__ w_g,
    const int* __restrict__ pos_map, const u16* __restrict__ Rd) {
  __shared__ __align__(16) u16 As[3][128 * 64];
  __shared__ __align__(16) u16 Bs[3][64 * 64];

  const int cpx = gridDim.x >> 3;
  const int wg = (blockIdx.x & 7) * cpx + (blockIdx.x >> 3);

  const int NT = N >> 6;
  int mt, nt, cnt = M, obase = 0;
  const u16* A = Abase;
  const u16* B = Bbase;

  if constexpr (EPI == 1) {
    mt = wg / NT;
    nt = wg - mt * NT;
  } else {
    const int per_e = MAXMT * NT;
    int e = wg / per_e;
    int r = wg - e * per_e;
    mt = r / NT;
    nt = r - mt * NT;
    cnt = counts[e];
    if (mt * 128 >= cnt) return;
    obase = offsets[e];
    A = Abase + (size_t)obase * I_DIM;
    B = Bbase + (size_t)e * (H_DIM * I_DIM);
  }

  const int tid = threadIdx.x;
  const int srow = tid >> 3;
  const int slot = tid & 7;
  const u16* gA[4];
#pragma unroll
  for (int p = 0; p < 4; ++p) {
    int rloc = p * 32 + srow;
    int ks = ((slot ^ (rloc & 7)) << 3);
    int am = mt * 128 + rloc;
    if constexpr (EPI == 3) {
      gA[p] = A + (size_t)((am < cnt) ? am : 0) * K + ks;
    } else {
      gA[p] = A + (size_t)am * K + ks;
    }
  }
  const u16* gB[2];
#pragma unroll
  for (int p = 0; p < 2; ++p) {
    int rloc = p * 32 + srow;
    int ks = ((slot ^ (rloc & 7)) << 3);
    gB[p] = B + (size_t)(nt * 64 + rloc) * K + ks;
  }

  const int wave = tid >> 6;
  const int lane = tid & 63;
  const int wr = wave >> 1;
  const int wc = wave & 1;
  const int frow = lane & 15;
  const int l4 = lane >> 4;

  int a_off[4][2], b_off[2][2];
#pragma unroll
  for (int m = 0; m < 4; ++m) {
    int row = wr * 64 + m * 16 + frow;
#pragma unroll
    for (int kk = 0; kk < 2; ++kk)
      a_off[m][kk] = (row << 6) + ((((kk << 2) + l4) ^ (row & 7)) << 3);
  }
#pragma unroll
  for (int n = 0; n < 2; ++n) {
    int row = wc * 32 + n * 16 + frow;
#pragma unroll
    for (int kk = 0; kk < 2; ++kk)
      b_off[n][kk] = (row << 6) + ((((kk << 2) + l4) ^ (row & 7)) << 3);
  }

  f32x4 acc[4][2];
#pragma unroll
  for (int m = 0; m < 4; ++m)
#pragma unroll
    for (int n = 0; n < 2; ++n) acc[m][n] = (f32x4)0.0f;

  const int dst = tid << 3;
  auto stage = [&](int k0, int c) {
#pragma unroll
    for (int p = 0; p < 4; ++p)
      gload16(gA[p] + k0, &As[c][(p << 11) + dst]);
#pragma unroll
    for (int p = 0; p < 2; ++p)
      gload16(gB[p] + k0, &Bs[c][(p << 11) + dst]);
  };

  const int KT = K >> 6;
  stage(0, 0);
  stage(64, 1);
  int cb = 0, sb = 2;
  for (int kt = 0; kt < KT; ++kt) {
    if (kt < KT - 1) {
      asm volatile("s_waitcnt vmcnt(6)" ::: "memory");
    } else {
      asm volatile("s_waitcnt vmcnt(0)" ::: "memory");
    }
    __builtin_amdgcn_s_barrier();
    __builtin_amdgcn_sched_barrier(0);
    if (kt + 2 < KT) stage((kt + 2) << 6, sb);
#pragma unroll
    for (int kk = 0; kk < 2; ++kk) {
      short8 a[4], b[2];
#pragma unroll
      for (int m = 0; m < 4; ++m)
        a[m] = *reinterpret_cast<const short8*>(&As[cb][a_off[m][kk]]);
#pragma unroll
      for (int n = 0; n < 2; ++n)
        b[n] = *reinterpret_cast<const short8*>(&Bs[cb][b_off[n][kk]]);
      __builtin_amdgcn_s_setprio(1);
#pragma unroll
      for (int m = 0; m < 4; ++m)
#pragma unroll
        for (int n = 0; n < 2; ++n)
          acc[m][n] = __builtin_amdgcn_mfma_f32_16x16x32_bf16(a[m], b[n], acc[m][n], 0, 0, 0);
      __builtin_amdgcn_s_setprio(0);
    }
    cb = (cb == 2) ? 0 : cb + 1;
    sb = (sb == 2) ? 0 : sb + 1;
  }

  const int rbase = l4 << 2;
  const int cbase = frow;
#pragma unroll
  for (int m = 0; m < 4; ++m) {
#pragma unroll
    for (int r = 0; r < 4; ++r) {
      int lr = wr * 64 + (m << 4) + rbase + r;
      int grow = mt * 128 + lr;
      if (EPI == 3 && grow >= cnt) continue;
      const int* pm = nullptr;
      if constexpr (EPI == 1) pm = pos_map + grow * TOPK;
#pragma unroll
      for (int n = 0; n < 2; ++n) {
        int gc = nt * 64 + wc * 32 + (n << 4) + cbase;
        float v = acc[m][n][r];
        if constexpr (EPI == 1) {
          v += bf2f(Rd[(size_t)pm[0] * H_DIM + gc]);
          v += bf2f(Rd[(size_t)pm[1] * H_DIM + gc]);
          v += bf2f(Rd[(size_t)pm[2] * H_DIM + gc]);
          v += bf2f(Rd[(size_t)pm[3] * H_DIM + gc]);
          Cf[(size_t)grow * N + gc] = v;
        } else {
          Cb[(size_t)(obase + grow) * N + gc] = f2bf(v);
        }
      }
    }
  }
}

// ---------------- launch ----------------
extern "C" void kernel_launch(void* const* d_in, const int* in_sizes, int n_in,
                              void* d_out, int out_size, void* d_ws, size_t ws_size,
                              hipStream_t stream) {
  const float* x = (const float*)d_in[0];
  const float* rw = (const float*)d_in[1];
  const float* bias = (const float*)d_in[2];
  const float* w_up = (const float*)d_in[3];
  const float* w_down = (const float*)d_in[4];
  const float* ws_up = (const float*)d_in[5];
  const float* ws_down = (const float*)d_in[6];
  float* out = (float*)d_out;

  uint8_t* wsb = (uint8_t*)d_ws;
  size_t off = 0;
  auto alloc = [&](size_t bytes) {
    void* p = wsb + off;
    off += (bytes + 255) & ~(size_t)255;
    return p;
  };
  u16* x_bf = (u16*)alloc((size_t)T_TOK * H_DIM * 2);
  u16* wsup_bf = (u16*)alloc((size_t)IS_DIM * H_DIM * 2);
  u16* wsdn_bf = (u16*)alloc((size_t)H_DIM * IS_DIM * 2);
  u16* wup_bf = (u16*)alloc((size_t)E_NUM * I_DIM * H_DIM * 2);
  u16* wdn_bf = (u16*)alloc((size_t)E_NUM * H_DIM * I_DIM * 2);
  u16* hs = (u16*)alloc((size_t)T_TOK * IS_DIM * 2);
  u16* hp = (u16*)alloc((size_t)(T_TOK * TOPK + 128) * I_DIM * 2);
  u16* hp_down = (u16*)alloc((size_t)(T_TOK * TOPK + 128) * H_DIM * 2);
  int* counts = (int*)alloc(64);
  int* offsets = (int*)alloc(128);
  int* tok_g = (int*)alloc((size_t)(T_TOK * TOPK) * 4);
  float* w_g = (float*)alloc((size_t)(T_TOK * TOPK) * 4);
  int* pos_map = (int*)alloc((size_t)(T_TOK * TOPK) * 4);
  int* tidx_buf = (int*)alloc((size_t)T_TOK * TOPK * 4);
  float* tw_buf = (float*)alloc((size_t)T_TOK * TOPK * 4);
  int* partial = (int*)alloc((size_t)NCHUNK * E_NUM * 4);
  int* chunk_base = (int*)alloc((size_t)NCHUNK * E_NUM * 4);

  route_kernel<<<T_TOK / 4, 256, 0, stream>>>(x, rw, bias, tidx_buf, tw_buf, x_bf);
  hist_kernel<<<NCHUNK, 256, 0, stream>>>(tidx_buf, partial);
  prefix2_kernel<<<1, 256, 0, stream>>>(partial, chunk_base, counts, offsets);
  scatter2_kernel<<<NCHUNK, 256, 0, stream>>>(tidx_buf, tw_buf, chunk_base,
                                              tok_g, w_g, pos_map);
  cvt_w_kernel<<<CVT_NB, 256, 0, stream>>>(
      ws_up, ws_down, w_up, w_down, wsup_bf, wsdn_bf, wup_bf, wdn_bf);

  // merged shared-up + routed-up (type-interleaved, relu^2 epilogues)
  gemm_up<<<NB_UP, 256, 0, stream>>>(
      x_bf, wsup_bf, wup_bf, hs, hp, counts, offsets, tok_g, w_g);
  // routed down: hp x w_down[e]^T -> hp_down bf16 (plain store)
  gemm_bt<3><<<E_NUM * MAXMT * (H_DIM / 64), 256, 0, stream>>>(
      hp, wdn_bf, nullptr, hp_down, T_TOK, H_DIM, I_DIM,
      counts, offsets, tok_g, w_g, nullptr, nullptr);
  // shared down + routed gather: hs x [H,IS]^T + sum_k hp_down -> out
  gemm_bt<1><<<(T_TOK / 128) * (H_DIM / 64), 256, 0, stream>>>(
      hs, wsdn_bf, out, nullptr, T_TOK, H_DIM, IS_DIM,
      nullptr, nullptr, nullptr, nullptr, pos_map, hp_down);
}

// Round 19
// 193.856 us; speedup vs baseline: 1.1520x; 1.1520x over previous
//
#include <hip/hip_runtime.h>
#include <stdint.h>

#define T_TOK 4096
#define H_DIM 1024
#define E_NUM 16
#define I_DIM 512
#define IS_DIM 2048
#define TOPK 4
#define NGRP 4
#define GSZ 4
#define MAXMT 32
#define NCHUNK 64  // (T_TOK*TOPK)/256

// weight-cvt segment boundaries in float4 units (wsu, wsd, wu, wd)
#define W0 524288
#define W1 1048576
#define W2 3145728
#define W3 5242880
#define CVT_NB 2048

typedef unsigned short u16;
typedef __attribute__((ext_vector_type(8))) short short8;
typedef __attribute__((ext_vector_type(4))) float f32x4;

__device__ __forceinline__ void gload16(const void* g, void* l) {
  __builtin_amdgcn_global_load_lds(
      (const __attribute__((address_space(1))) void*)g,
      (__attribute__((address_space(3))) void*)l, 16, 0, 0);
}

__device__ __forceinline__ u16 f2bf(float f) {
  union { float f; uint32_t u; } v; v.f = f;
  uint32_t u = v.u;
  uint32_t r = (u + 0x7fffu + ((u >> 16) & 1u)) >> 16;
  return (u16)r;
}

__device__ __forceinline__ float bf2f(u16 h) {
  union { uint32_t u; float f; } v; v.u = ((uint32_t)h) << 16;
  return v.f;
}

// ---------------- weights fp32 -> bf16 (grid-stride, 4 segments) ----------
__global__ __launch_bounds__(256) void cvt_w_kernel(
    const float* __restrict__ wsu, const float* __restrict__ wsd,
    const float* __restrict__ wu, const float* __restrict__ wd,
    u16* __restrict__ wsub, u16* __restrict__ wsdb,
    u16* __restrict__ wub, u16* __restrict__ wdb) {
  for (int i = blockIdx.x * 256 + threadIdx.x; i < W3; i += CVT_NB * 256) {
    const float4* src; ushort4* dst; int base;
    if (i < W0)      { src = (const float4*)wsu; dst = (ushort4*)wsub; base = 0;  }
    else if (i < W1) { src = (const float4*)wsd; dst = (ushort4*)wsdb; base = W0; }
    else if (i < W2) { src = (const float4*)wu;  dst = (ushort4*)wub;  base = W1; }
    else             { src = (const float4*)wd;  dst = (ushort4*)wdb;  base = W2; }
    float4 v = src[i - base];
    ushort4 o;
    o.x = f2bf(v.x); o.y = f2bf(v.y); o.z = f2bf(v.z); o.w = f2bf(v.w);
    dst[i - base] = o;
  }
}

// ------- routing: per-token top-4 (no atomics) + x fp32->bf16 side-write ---
__global__ __launch_bounds__(256) void route_kernel(
    const float* __restrict__ x, const float* __restrict__ rw,
    const float* __restrict__ bias, int* __restrict__ tidx_out,
    float* __restrict__ tw_out, u16* __restrict__ x_bf) {
  const int wave = threadIdx.x >> 6;
  const int lane = threadIdx.x & 63;
  const int t = blockIdx.x * 4 + wave;

  const float4* xr = reinterpret_cast<const float4*>(x + (size_t)t * H_DIM);
  const float4* rw4 = reinterpret_cast<const float4*>(rw);
  ushort4* xbw = reinterpret_cast<ushort4*>(x_bf + (size_t)t * H_DIM);
  float4 xv[4];
#pragma unroll
  for (int j = 0; j < 4; ++j) xv[j] = xr[lane + j * 64];
#pragma unroll
  for (int j = 0; j < 4; ++j) {
    ushort4 o;
    o.x = f2bf(xv[j].x); o.y = f2bf(xv[j].y);
    o.z = f2bf(xv[j].z); o.w = f2bf(xv[j].w);
    xbw[lane + j * 64] = o;
  }

  double acc[E_NUM];
#pragma unroll
  for (int e = 0; e < E_NUM; ++e) {
    double a = 0.0;
#pragma unroll
    for (int j = 0; j < 4; ++j) {
      float4 w = rw4[e * 256 + lane + j * 64];
      a += (double)xv[j].x * (double)w.x;
      a += (double)xv[j].y * (double)w.y;
      a += (double)xv[j].z * (double)w.z;
      a += (double)xv[j].w * (double)w.w;
    }
    acc[e] = a;
  }
#pragma unroll
  for (int e = 0; e < E_NUM; ++e) {
#pragma unroll
    for (int off = 32; off; off >>= 1) acc[e] += __shfl_xor(acc[e], off);
  }
  if (lane == 0) {
    float scores[E_NUM], sfc[E_NUM];
#pragma unroll
    for (int e = 0; e < E_NUM; ++e) {
      scores[e] = 1.0f / (1.0f + expf((float)(-acc[e])));
      sfc[e] = scores[e] + bias[e];
    }
    float gs[NGRP];
#pragma unroll
    for (int g = 0; g < NGRP; ++g) {
      float m1 = -1e30f, m2 = -1e30f;
#pragma unroll
      for (int j = 0; j < GSZ; ++j) {
        float v = sfc[g * GSZ + j];
        if (v > m1) { m2 = m1; m1 = v; } else if (v > m2) { m2 = v; }
      }
      gs[g] = m1 + m2;
    }
    int g1 = 0;
    for (int g = 1; g < NGRP; ++g) if (gs[g] > gs[g1]) g1 = g;
    int g2 = -1;
    for (int g = 0; g < NGRP; ++g) {
      if (g == g1) continue;
      if (g2 < 0 || gs[g] > gs[g2]) g2 = g;
    }
    float masked[E_NUM];
#pragma unroll
    for (int e = 0; e < E_NUM; ++e) {
      int g = e / GSZ;
      masked[e] = (g == g1 || g == g2) ? sfc[e] : 0.0f;
    }
    int tidx[TOPK]; float tw[TOPK];
#pragma unroll
    for (int k = 0; k < TOPK; ++k) {
      int best = 0; float bv = masked[0];
      for (int e = 1; e < E_NUM; ++e)
        if (masked[e] > bv) { bv = masked[e]; best = e; }
      tidx[k] = best; tw[k] = scores[best]; masked[best] = -1e30f;
    }
    float s = tw[0] + tw[1] + tw[2] + tw[3] + 1e-20f;
#pragma unroll
    for (int k = 0; k < TOPK; ++k) {
      tidx_out[t * TOPK + k] = tidx[k];
      tw_out[t * TOPK + k] = tw[k] / s * 2.5f;
    }
  }
}

// ---------------- chunk histogram (64 blocks, one barrier) ----------------
__global__ __launch_bounds__(256) void hist_kernel(const int* __restrict__ tidx,
                                                   int* __restrict__ partial) {
  const int c = blockIdx.x;
  const int tid = threadIdx.x;
  const int lane = tid & 63;
  const int w = tid >> 6;
  __shared__ int h[4][E_NUM];
  const int e = tidx[c * 256 + tid];
#pragma unroll
  for (int ee = 0; ee < E_NUM; ++ee) {
    unsigned long long b = __ballot(e == ee);
    if (lane == 0) h[w][ee] = __popcll(b);
  }
  __syncthreads();
  if (tid < E_NUM)
    partial[c * E_NUM + tid] = h[0][tid] + h[1][tid] + h[2][tid] + h[3][tid];
}

// ------- per-expert chunk bases + expert offsets (1 block) -------
__global__ __launch_bounds__(256) void prefix2_kernel(
    const int* __restrict__ partial, int* __restrict__ chunk_base,
    int* __restrict__ counts, int* __restrict__ offsets) {
  __shared__ int tot[E_NUM];
  __shared__ int offs[E_NUM];
  const int tid = threadIdx.x;
  if (tid < E_NUM) {
    int run = 0;
    for (int c = 0; c < NCHUNK; ++c) {
      chunk_base[c * E_NUM + tid] = run;
      run += partial[c * E_NUM + tid];
    }
    tot[tid] = run;
    counts[tid] = run;
  }
  __syncthreads();
  if (tid == 0) {
    int s = 0;
    for (int e = 0; e < E_NUM; ++e) { offs[e] = s; offsets[e] = s; s += tot[e]; }
    offsets[E_NUM] = s;
  }
  __syncthreads();
  for (int i = tid; i < NCHUNK * E_NUM; i += 256)
    chunk_base[i] += offs[i & 15];
}

// ---------------- scatter (64 blocks, one barrier) ----------------
__global__ __launch_bounds__(256) void scatter2_kernel(
    const int* __restrict__ tidx, const float* __restrict__ tw,
    const int* __restrict__ chunk_base,
    int* __restrict__ tok_g, float* __restrict__ w_g, int* __restrict__ pos_map) {
  const int c = blockIdx.x;
  const int tid = threadIdx.x;
  const int lane = tid & 63;
  const int w = tid >> 6;
  __shared__ int h[4][E_NUM];
  const int i = c * 256 + tid;
  const int e = tidx[i];
  int pre = 0;
#pragma unroll
  for (int ee = 0; ee < E_NUM; ++ee) {
    unsigned long long b = __ballot(e == ee);
    if (lane == 0) h[w][ee] = __popcll(b);
    if (ee == e) pre = __popcll(b & ((1ull << lane) - 1ull));
  }
  __syncthreads();
  int rank = pre;
  for (int ww = 0; ww < w; ++ww) rank += h[ww][e];
  const int pos = chunk_base[c * E_NUM + e] + rank;
  tok_g[pos] = i >> 2;
  w_g[pos] = tw[i];
  pos_map[i] = pos;
}

// ---- merged UP GEMM: shared-up + routed-up, type-interleaved mod 5 -------
// 128x64 tile, 4 waves (2Mx2N of 64x32), BK=64, dbuf 48KB LDS, 3 blocks/CU.
#define NB_UP 5120
__global__ __launch_bounds__(256, 3) void gemm_up(
    const u16* __restrict__ x_bf, const u16* __restrict__ wsup_bf,
    const u16* __restrict__ wup_bf, u16* __restrict__ hs, u16* __restrict__ hp,
    const int* __restrict__ counts, const int* __restrict__ offsets,
    const int* __restrict__ tok_g, const float* __restrict__ w_g) {
  __shared__ __align__(16) u16 As[2][128 * 64];  // 32 KB
  __shared__ __align__(16) u16 Bs[2][64 * 64];   // 16 KB

  const int cpx = gridDim.x >> 3;
  const int wg = (blockIdx.x & 7) * cpx + (blockIdx.x >> 3);
  const int q = wg / 5;
  const int r5 = wg - q * 5;
  const bool shared = (r5 == 0);

  int mt, nt, cnt, obase = 0;
  const u16* B;
  if (shared) {
    mt = q >> 5;            // IS_DIM/64 = 32 n-tiles
    nt = q & 31;
    cnt = T_TOK;
    B = wsup_bf;
  } else {
    int rid = q * 4 + (r5 - 1);       // 0..4095
    int e = rid >> 8;                 // 256 slots/expert
    int r = rid & 255;
    mt = r >> 3;                      // MAXMT=32 m-tiles
    nt = r & 7;                       // I_DIM/64 = 8 n-tiles
    cnt = counts[e];
    if (mt * 128 >= cnt) return;
    obase = offsets[e];
    B = wup_bf + (size_t)e * (I_DIM * H_DIM);
  }
  const int K = H_DIM;

  const int tid = threadIdx.x;
  const int srow = tid >> 3;
  const int slot = tid & 7;
  const u16* gA[4];
#pragma unroll
  for (int p = 0; p < 4; ++p) {
    int rloc = p * 32 + srow;
    int ks = ((slot ^ (rloc & 7)) << 3);
    int am = mt * 128 + rloc;
    int row;
    if (shared) row = am;
    else row = tok_g[obase + ((am < cnt) ? am : 0)];
    gA[p] = x_bf + (size_t)row * H_DIM + ks;
  }
  const u16* gB[2];
#pragma unroll
  for (int p = 0; p < 2; ++p) {
    int rloc = p * 32 + srow;
    int ks = ((slot ^ (rloc & 7)) << 3);
    gB[p] = B + (size_t)(nt * 64 + rloc) * K + ks;
  }

  const int wave = tid >> 6;
  const int lane = tid & 63;
  const int wr = wave >> 1;
  const int wc = wave & 1;
  const int frow = lane & 15;
  const int l4 = lane >> 4;

  int a_off[4][2], b_off[2][2];
#pragma unroll
  for (int m = 0; m < 4; ++m) {
    int row = wr * 64 + m * 16 + frow;
#pragma unroll
    for (int kk = 0; kk < 2; ++kk)
      a_off[m][kk] = (row << 6) + ((((kk << 2) + l4) ^ (row & 7)) << 3);
  }
#pragma unroll
  for (int n = 0; n < 2; ++n) {
    int row = wc * 32 + n * 16 + frow;
#pragma unroll
    for (int kk = 0; kk < 2; ++kk)
      b_off[n][kk] = (row << 6) + ((((kk << 2) + l4) ^ (row & 7)) << 3);
  }

  f32x4 acc[4][2];
#pragma unroll
  for (int m = 0; m < 4; ++m)
#pragma unroll
    for (int n = 0; n < 2; ++n) acc[m][n] = (f32x4)0.0f;

  const int dst = tid << 3;
  auto stage = [&](int k0, int c) {
#pragma unroll
    for (int p = 0; p < 4; ++p)
      gload16(gA[p] + k0, &As[c][(p << 11) + dst]);
#pragma unroll
    for (int p = 0; p < 2; ++p)
      gload16(gB[p] + k0, &Bs[c][(p << 11) + dst]);
  };

  const int KT = K >> 6;
  stage(0, 0);
  int cur = 0;
  for (int kt = 0; kt < KT; ++kt) {
    __syncthreads();
    if (kt + 1 < KT) stage((kt + 1) << 6, cur ^ 1);
#pragma unroll
    for (int kk = 0; kk < 2; ++kk) {
      short8 a[4], b[2];
#pragma unroll
      for (int m = 0; m < 4; ++m)
        a[m] = *reinterpret_cast<const short8*>(&As[cur][a_off[m][kk]]);
#pragma unroll
      for (int n = 0; n < 2; ++n)
        b[n] = *reinterpret_cast<const short8*>(&Bs[cur][b_off[n][kk]]);
      __builtin_amdgcn_s_setprio(1);
#pragma unroll
      for (int m = 0; m < 4; ++m)
#pragma unroll
        for (int n = 0; n < 2; ++n)
          acc[m][n] = __builtin_amdgcn_mfma_f32_16x16x32_bf16(a[m], b[n], acc[m][n], 0, 0, 0);
      __builtin_amdgcn_s_setprio(0);
    }
    cur ^= 1;
  }

  const int rbase = l4 << 2;
  const int cbase = frow;
#pragma unroll
  for (int m = 0; m < 4; ++m) {
#pragma unroll
    for (int r = 0; r < 4; ++r) {
      int lr = wr * 64 + (m << 4) + rbase + r;
      int grow = mt * 128 + lr;
      if (!shared && grow >= cnt) continue;
      float wv = shared ? 1.0f : w_g[obase + grow];
#pragma unroll
      for (int n = 0; n < 2; ++n) {
        int gc = nt * 64 + wc * 32 + (n << 4) + cbase;
        float v = acc[m][n][r];
        float tpos = fmaxf(v, 0.0f);
        float o = tpos * tpos * wv;
        if (shared) hs[(size_t)grow * IS_DIM + gc] = f2bf(o);
        else hp[(size_t)(obase + grow) * I_DIM + gc] = f2bf(o);
      }
    }
  }
}

// ---- bf16 MFMA GEMM down-path: C = A * B^T (R8/R11 structure) ------------
// EPI 1: shared-down : out[t] = acc + sum_k bf2f(Rd[pos_map[t*4+k]])
// EPI 3: routed-down : C=Rd bf16 plain store at row obase+grow
template <int EPI>
__global__ __launch_bounds__(256, 3) void gemm_bt(
    const u16* __restrict__ Abase, const u16* __restrict__ Bbase,
    float* __restrict__ Cf, u16* __restrict__ Cb,
    int M, int N, int K,
    const int* __restrict__ counts, const int* __restrict__ offsets,
    const int* __restrict__ tok_g, const float* __restrict__ w_g,
    const int* __restrict__ pos_map, const u16* __restrict__ Rd) {
  __shared__ __align__(16) u16 As[2][128 * 64];
  __shared__ __align__(16) u16 Bs[2][64 * 64];

  const int cpx = gridDim.x >> 3;
  const int wg = (blockIdx.x & 7) * cpx + (blockIdx.x >> 3);

  const int NT = N >> 6;
  int mt, nt, cnt = M, obase = 0;
  const u16* A = Abase;
  const u16* B = Bbase;

  if constexpr (EPI == 1) {
    mt = wg / NT;
    nt = wg - mt * NT;
  } else {
    const int per_e = MAXMT * NT;
    int e = wg / per_e;
    int r = wg - e * per_e;
    mt = r / NT;
    nt = r - mt * NT;
    cnt = counts[e];
    if (mt * 128 >= cnt) return;
    obase = offsets[e];
    A = Abase + (size_t)obase * I_DIM;
    B = Bbase + (size_t)e * (H_DIM * I_DIM);
  }

  const int tid = threadIdx.x;
  const int srow = tid >> 3;
  const int slot = tid & 7;
  const u16* gA[4];
#pragma unroll
  for (int p = 0; p < 4; ++p) {
    int rloc = p * 32 + srow;
    int ks = ((slot ^ (rloc & 7)) << 3);
    int am = mt * 128 + rloc;
    if constexpr (EPI == 3) {
      gA[p] = A + (size_t)((am < cnt) ? am : 0) * K + ks;
    } else {
      gA[p] = A + (size_t)am * K + ks;
    }
  }
  const u16* gB[2];
#pragma unroll
  for (int p = 0; p < 2; ++p) {
    int rloc = p * 32 + srow;
    int ks = ((slot ^ (rloc & 7)) << 3);
    gB[p] = B + (size_t)(nt * 64 + rloc) * K + ks;
  }

  const int wave = tid >> 6;
  const int lane = tid & 63;
  const int wr = wave >> 1;
  const int wc = wave & 1;
  const int frow = lane & 15;
  const int l4 = lane >> 4;

  int a_off[4][2], b_off[2][2];
#pragma unroll
  for (int m = 0; m < 4; ++m) {
    int row = wr * 64 + m * 16 + frow;
#pragma unroll
    for (int kk = 0; kk < 2; ++kk)
      a_off[m][kk] = (row << 6) + ((((kk << 2) + l4) ^ (row & 7)) << 3);
  }
#pragma unroll
  for (int n = 0; n < 2; ++n) {
    int row = wc * 32 + n * 16 + frow;
#pragma unroll
    for (int kk = 0; kk < 2; ++kk)
      b_off[n][kk] = (row << 6) + ((((kk << 2) + l4) ^ (row & 7)) << 3);
  }

  f32x4 acc[4][2];
#pragma unroll
  for (int m = 0; m < 4; ++m)
#pragma unroll
    for (int n = 0; n < 2; ++n) acc[m][n] = (f32x4)0.0f;

  const int dst = tid << 3;
  auto stage = [&](int k0, int c) {
#pragma unroll
    for (int p = 0; p < 4; ++p)
      gload16(gA[p] + k0, &As[c][(p << 11) + dst]);
#pragma unroll
    for (int p = 0; p < 2; ++p)
      gload16(gB[p] + k0, &Bs[c][(p << 11) + dst]);
  };

  const int KT = K >> 6;
  stage(0, 0);
  int cur = 0;
  for (int kt = 0; kt < KT; ++kt) {
    __syncthreads();
    if (kt + 1 < KT) stage((kt + 1) << 6, cur ^ 1);
#pragma unroll
    for (int kk = 0; kk < 2; ++kk) {
      short8 a[4], b[2];
#pragma unroll
      for (int m = 0; m < 4; ++m)
        a[m] = *reinterpret_cast<const short8*>(&As[cur][a_off[m][kk]]);
#pragma unroll
      for (int n = 0; n < 2; ++n)
        b[n] = *reinterpret_cast<const short8*>(&Bs[cur][b_off[n][kk]]);
      __builtin_amdgcn_s_setprio(1);
#pragma unroll
      for (int m = 0; m < 4; ++m)
#pragma unroll
        for (int n = 0; n < 2; ++n)
          acc[m][n] = __builtin_amdgcn_mfma_f32_16x16x32_bf16(a[m], b[n], acc[m][n], 0, 0, 0);
      __builtin_amdgcn_s_setprio(0);
    }
    cur ^= 1;
  }

  const int rbase = l4 << 2;
  const int cbase = frow;
#pragma unroll
  for (int m = 0; m < 4; ++m) {
#pragma unroll
    for (int r = 0; r < 4; ++r) {
      int lr = wr * 64 + (m << 4) + rbase + r;
      int grow = mt * 128 + lr;
      if (EPI == 3 && grow >= cnt) continue;
      const int* pm = nullptr;
      if constexpr (EPI == 1) pm = pos_map + grow * TOPK;
#pragma unroll
      for (int n = 0; n < 2; ++n) {
        int gc = nt * 64 + wc * 32 + (n << 4) + cbase;
        float v = acc[m][n][r];
        if constexpr (EPI == 1) {
          v += bf2f(Rd[(size_t)pm[0] * H_DIM + gc]);
          v += bf2f(Rd[(size_t)pm[1] * H_DIM + gc]);
          v += bf2f(Rd[(size_t)pm[2] * H_DIM + gc]);
          v += bf2f(Rd[(size_t)pm[3] * H_DIM + gc]);
          Cf[(size_t)grow * N + gc] = v;
        } else {
          Cb[(size_t)(obase + grow) * N + gc] = f2bf(v);
        }
      }
    }
  }
}

// ---------------- launch ----------------
extern "C" void kernel_launch(void* const* d_in, const int* in_sizes, int n_in,
                              void* d_out, int out_size, void* d_ws, size_t ws_size,
                              hipStream_t stream) {
  const float* x = (const float*)d_in[0];
  const float* rw = (const float*)d_in[1];
  const float* bias = (const float*)d_in[2];
  const float* w_up = (const float*)d_in[3];
  const float* w_down = (const float*)d_in[4];
  const float* ws_up = (const float*)d_in[5];
  const float* ws_down = (const float*)d_in[6];
  float* out = (float*)d_out;

  uint8_t* wsb = (uint8_t*)d_ws;
  size_t off = 0;
  auto alloc = [&](size_t bytes) {
    void* p = wsb + off;
    off += (bytes + 255) & ~(size_t)255;
    return p;
  };
  u16* x_bf = (u16*)alloc((size_t)T_TOK * H_DIM * 2);
  u16* wsup_bf = (u16*)alloc((size_t)IS_DIM * H_DIM * 2);
  u16* wsdn_bf = (u16*)alloc((size_t)H_DIM * IS_DIM * 2);
  u16* wup_bf = (u16*)alloc((size_t)E_NUM * I_DIM * H_DIM * 2);
  u16* wdn_bf = (u16*)alloc((size_t)E_NUM * H_DIM * I_DIM * 2);
  u16* hs = (u16*)alloc((size_t)T_TOK * IS_DIM * 2);
  u16* hp = (u16*)alloc((size_t)(T_TOK * TOPK + 128) * I_DIM * 2);
  u16* hp_down = (u16*)alloc((size_t)(T_TOK * TOPK + 128) * H_DIM * 2);
  int* counts = (int*)alloc(64);
  int* offsets = (int*)alloc(128);
  int* tok_g = (int*)alloc((size_t)(T_TOK * TOPK) * 4);
  float* w_g = (float*)alloc((size_t)(T_TOK * TOPK) * 4);
  int* pos_map = (int*)alloc((size_t)(T_TOK * TOPK) * 4);
  int* tidx_buf = (int*)alloc((size_t)T_TOK * TOPK * 4);
  float* tw_buf = (float*)alloc((size_t)T_TOK * TOPK * 4);
  int* partial = (int*)alloc((size_t)NCHUNK * E_NUM * 4);
  int* chunk_base = (int*)alloc((size_t)NCHUNK * E_NUM * 4);

  route_kernel<<<T_TOK / 4, 256, 0, stream>>>(x, rw, bias, tidx_buf, tw_buf, x_bf);
  hist_kernel<<<NCHUNK, 256, 0, stream>>>(tidx_buf, partial);
  prefix2_kernel<<<1, 256, 0, stream>>>(partial, chunk_base, counts, offsets);
  scatter2_kernel<<<NCHUNK, 256, 0, stream>>>(tidx_buf, tw_buf, chunk_base,
                                              tok_g, w_g, pos_map);
  cvt_w_kernel<<<CVT_NB, 256, 0, stream>>>(
      ws_up, ws_down, w_up, w_down, wsup_bf, wsdn_bf, wup_bf, wdn_bf);

  // merged shared-up + routed-up (type-interleaved, relu^2 epilogues)
  gemm_up<<<NB_UP, 256, 0, stream>>>(
      x_bf, wsup_bf, wup_bf, hs, hp, counts, offsets, tok_g, w_g);
  // routed down: hp x w_down[e]^T -> hp_down bf16 (plain store)
  gemm_bt<3><<<E_NUM * MAXMT * (H_DIM / 64), 256, 0, stream>>>(
      hp, wdn_bf, nullptr, hp_down, T_TOK, H_DIM, I_DIM,
      counts, offsets, tok_g, w_g, nullptr, nullptr);
  // shared down + routed gather: hs x [H,IS]^T + sum_k hp_down -> out
  gemm_bt<1><<<(T_TOK / 128) * (H_DIM / 64), 256, 0, stream>>>(
      hs, wsdn_bf, out, nullptr, T_TOK, H_DIM, IS_DIM,
      nullptr, nullptr, nullptr, nullptr, pos_map, hp_down);
}